// Round 6
// baseline (162.052 us; speedup 1.0000x reference)
//
#include <hip/hip_runtime.h>
#include <hip/hip_bf16.h>

// CrossViewAttention: B=4, V=6, C=256, H=W=64 (HW=4096), heads=8, dh=32.
//
// Pipeline (6 launches):
//   1. convert_weights: Wq/Wk/Wv/Wo fp32 -> bf16
//   2. transpose_mean:  x[b][v][c][w] -> xt[b][v][w][c] bf16, xbar[b][w][c] bf16 (mean over v)
//   3. gemm: Qloc[b][w][c] bf16 = xbar @ Wq^T     ([w][c] layout)
//   4. fused gemm: Kt = xt @ Wk^T AND Vt = xt @ Wv^T in one pass
//      - A (pixels) staged in LDS, 2-phase dbuf, counted vmcnt(2)
//      - B (weights) loaded per K-step straight into registers from L2 (no LDS, no barrier)
//   5. attn: one thread per (b,w,h) — contiguous 64B loads per head
//   6. gemm: d_out[b][o][w] fp32 = Wo @ attnT

typedef __bf16 bf16x8 __attribute__((ext_vector_type(8)));
typedef float f32x4 __attribute__((ext_vector_type(4)));

#define HW 4096
#define C_DIM 256
#define NV 6
#define NB 4

__global__ __launch_bounds__(256) void convert_weights_kernel(
    const float* __restrict__ Wq, const float* __restrict__ Wk,
    const float* __restrict__ Wv, const float* __restrict__ Wo,
    __hip_bfloat16* __restrict__ out)
{
    const float* srcs[4] = {Wq, Wk, Wv, Wo};
    const int m = blockIdx.y;
    const int i = blockIdx.x * 256 + threadIdx.x;
    out[m * 65536 + i] = __float2bfloat16(srcs[m][i]);
}

// 64x64 tile transpose via LDS; accumulates per-view sum for xbar.
__global__ __launch_bounds__(256) void transpose_mean_kernel(
    const float* __restrict__ x,        // [B][V][C][HW]
    __hip_bfloat16* __restrict__ xt,    // [B][V][HW][C]
    __hip_bfloat16* __restrict__ xbar)  // [B][HW][C]
{
    __shared__ float tile[64][65];
    const int w0 = blockIdx.x * 64;
    const int c0 = blockIdx.y * 64;
    const int b  = blockIdx.z;
    const int t  = threadIdx.x;
    const int li = t & 63;
    const int qi = t >> 6;
    float acc[16];
#pragma unroll
    for (int i = 0; i < 16; ++i) acc[i] = 0.f;

    for (int v = 0; v < NV; ++v) {
        const float* src = x + (((size_t)b * NV + v) * C_DIM + c0) * HW + w0;
#pragma unroll
        for (int i = 0; i < 16; ++i) {
            const int c = qi + 4 * i;
            tile[li][c] = src[(size_t)c * HW + li];
        }
        __syncthreads();
        __hip_bfloat16* dst = xt + (((size_t)b * NV + v) * HW + w0) * C_DIM + c0;
#pragma unroll
        for (int i = 0; i < 16; ++i) {
            const int w = qi + 4 * i;
            const float val = tile[w][li];
            acc[i] += val;
            dst[(size_t)w * C_DIM + li] = __float2bfloat16(val);
        }
        __syncthreads();
    }
    __hip_bfloat16* dbar = xbar + ((size_t)b * HW + w0) * C_DIM + c0;
#pragma unroll
    for (int i = 0; i < 16; ++i) {
        const int w = qi + 4 * i;
        dbar[(size_t)w * C_DIM + li] = __float2bfloat16(acc[i] * (1.f / 6.f));
    }
}

// Generic 128x128-tile GEMM, K=256:  C[z][row][col] = A_z[row][k] * B_z[col][k]
// 2-phase dbuf with counted vmcnt (unchanged from round 5 — proven).
template<int OUT_BF16>
__global__ __launch_bounds__(256) void gemm_generic(
    const __hip_bfloat16* __restrict__ Abase, size_t strideA,
    const __hip_bfloat16* __restrict__ Bbase, size_t strideB,
    void* __restrict__ Cv, size_t strideC, int ldc)
{
    __shared__ __align__(16) __hip_bfloat16 Alds[2][4096];  // [buf][kb 0..3][row 0..127][8]
    __shared__ __align__(16) __hip_bfloat16 Blds[2][4096];
    const int n0 = blockIdx.x * 128;
    const int m0 = blockIdx.y * 128;
    const int z  = blockIdx.z;
    const __hip_bfloat16* A = Abase + (size_t)z * strideA;
    const __hip_bfloat16* B = Bbase + (size_t)z * strideB;

    const int t  = threadIdx.x;
    const int wv = t >> 6, l = t & 63;
    const int wr = wv >> 1, wc = wv & 1;

    f32x4 acc[4][4];
#pragma unroll
    for (int i = 0; i < 4; ++i)
#pragma unroll
        for (int j = 0; j < 4; ++j) {
            acc[i][j][0] = 0.f; acc[i][j][1] = 0.f;
            acc[i][j][2] = 0.f; acc[i][j][3] = 0.f;
        }

    const int matB = wv >> 1;
    const __hip_bfloat16* gsrc = matB ? B : A;
    __hip_bfloat16* lds0 = matB ? &Blds[0][0] : &Alds[0][0];
    const int rbase = matB ? n0 : m0;

    const int kb_l = l >> 4;
    const int rl   = l & 15;

    auto stage = [&](int buf, int k0) {
#pragma unroll
        for (int c2 = 0; c2 < 4; ++c2) {
            const int c    = (wv & 1) * 4 + c2;   // 0..7 across the two waves
            const int kb   = c >> 1, half = c & 1;
            const int row  = half * 64 + l;
            const __hip_bfloat16* g = gsrc + (size_t)(rbase + row) * 256 + (k0 + kb * 8);
            __builtin_amdgcn_global_load_lds(
                (const __attribute__((address_space(1))) void*)g,
                (__attribute__((address_space(3))) void*)(lds0 + buf * 4096 + kb * 1024 + half * 512),
                16, 0, 0);
        }
    };

    stage(0, 0);
    stage(1, 32);

    for (int kt = 0; kt < 8; ++kt) {
        const int buf = kt & 1;
        if (kt < 7) asm volatile("s_waitcnt vmcnt(4)" ::: "memory");
        else        asm volatile("s_waitcnt vmcnt(0)" ::: "memory");
        __builtin_amdgcn_s_barrier();
        asm volatile("" ::: "memory");

        bf16x8 af[4], bfr[4];
#pragma unroll
        for (int i = 0; i < 4; ++i)
            af[i] = *(const bf16x8*)&Alds[buf][kb_l * 1024 + (wr * 64 + i * 16 + rl) * 8];
#pragma unroll
        for (int j = 0; j < 4; ++j)
            bfr[j] = *(const bf16x8*)&Blds[buf][kb_l * 1024 + (wc * 64 + j * 16 + rl) * 8];
#pragma unroll
        for (int i = 0; i < 4; ++i)
#pragma unroll
            for (int j = 0; j < 4; ++j)
                acc[i][j] = __builtin_amdgcn_mfma_f32_16x16x32_bf16(af[i], bfr[j], acc[i][j], 0, 0, 0);

        asm volatile("" ::: "memory");
        __builtin_amdgcn_s_barrier();
        asm volatile("" ::: "memory");
        if (kt + 2 < 8) stage(buf, (kt + 2) * 32);
    }

    const int r0 = (l >> 4) * 4;
    const int cl = l & 15;
#pragma unroll
    for (int i = 0; i < 4; ++i) {
        const int row = m0 + wr * 64 + i * 16 + r0;
#pragma unroll
        for (int j = 0; j < 4; ++j) {
            const int col = n0 + wc * 64 + j * 16 + cl;
            if (OUT_BF16) {
                __hip_bfloat16* Cp = (__hip_bfloat16*)Cv + (size_t)z * strideC;
#pragma unroll
                for (int r = 0; r < 4; ++r)
                    Cp[(size_t)(row + r) * ldc + col] = __float2bfloat16(acc[i][j][r]);
            } else {
                float* Cp = (float*)Cv + (size_t)z * strideC;
#pragma unroll
                for (int r = 0; r < 4; ++r)
                    Cp[(size_t)(row + r) * ldc + col] = acc[i][j][r];
            }
        }
    }
}

// Fused K/V GEMM. A (xt pixels) staged in LDS (2 chunks/wave/step, dbuf,
// counted vmcnt); Wk/Wv fragments loaded per K-step into registers from L2.
// Issue order guarantees: B(kt) issued before A(kt+1), so vmcnt(2) at iter kt
// retires A(kt)+B(kt) while A(kt+1) stays in flight (in-order retirement).
__global__ __launch_bounds__(256) void gemm_kv_kernel(
    const __hip_bfloat16* __restrict__ xt,   // [z][4096][256]
    const __hip_bfloat16* __restrict__ Wk,   // [256][256]
    const __hip_bfloat16* __restrict__ Wv,   // [256][256]
    __hip_bfloat16* __restrict__ Kt,         // [z][4096][256]
    __hip_bfloat16* __restrict__ Vt)         // [z][4096][256]
{
    __shared__ __align__(16) __hip_bfloat16 Alds[2][4096];   // [buf][kb][row 0..127][8]
    const int n0 = blockIdx.x * 128;
    const int m0 = blockIdx.y * 128;
    const int z  = blockIdx.z;
    const __hip_bfloat16* A = xt + (size_t)z * (HW * C_DIM);

    const int t  = threadIdx.x;
    const int wv = t >> 6, l = t & 63;
    const int wr = wv >> 1, wc = wv & 1;

    const int kb_l = l >> 4;
    const int rl   = l & 15;

    f32x4 acck[4][4], accv[4][4];
#pragma unroll
    for (int i = 0; i < 4; ++i)
#pragma unroll
        for (int j = 0; j < 4; ++j) {
#pragma unroll
            for (int r = 0; r < 4; ++r) { acck[i][j][r] = 0.f; accv[i][j][r] = 0.f; }
        }

    // B fragment base: row = n0 + wc*64 + j*16 + rl, k = k0 + kb_l*8
    const __hip_bfloat16* bkbase = Wk + (size_t)(n0 + wc * 64 + rl) * 256 + kb_l * 8;
    const __hip_bfloat16* bvbase = Wv + (size_t)(n0 + wc * 64 + rl) * 256 + kb_l * 8;

    // stage A K-step into LDS buffer: 2 chunks per wave (kb = wv, halves 0/1)
    auto stage = [&](int buf, int k0) {
#pragma unroll
        for (int half = 0; half < 2; ++half) {
            const int row = half * 64 + l;
            const __hip_bfloat16* g = A + (size_t)(m0 + row) * 256 + k0 + wv * 8;
            __builtin_amdgcn_global_load_lds(
                (const __attribute__((address_space(1))) void*)g,
                (__attribute__((address_space(3))) void*)(&Alds[0][0] + buf * 4096 + wv * 1024 + half * 512),
                16, 0, 0);
        }
    };

    bf16x8 bk[4], bv[4];

    // prologue: A0, B0, A1  (B0 before A1 so vmcnt(2) at iter0 keeps A1 in flight)
    stage(0, 0);
#pragma unroll
    for (int j = 0; j < 4; ++j) {
        bk[j] = *(const bf16x8*)(bkbase + j * 4096);
        bv[j] = *(const bf16x8*)(bvbase + j * 4096);
    }
    stage(1, 32);

    for (int kt = 0; kt < 8; ++kt) {
        const int buf = kt & 1;
        // retire A(kt) + B(kt); allow A(kt+1) (2 per-wave ops) in flight
        if (kt < 7) asm volatile("s_waitcnt vmcnt(2)" ::: "memory");
        else        asm volatile("s_waitcnt vmcnt(0)" ::: "memory");
        __builtin_amdgcn_s_barrier();
        asm volatile("" ::: "memory");

        bf16x8 af[4];
#pragma unroll
        for (int i = 0; i < 4; ++i)
            af[i] = *(const bf16x8*)&Alds[buf][kb_l * 1024 + (wr * 64 + i * 16 + rl) * 8];

#pragma unroll
        for (int i = 0; i < 4; ++i)
#pragma unroll
            for (int j = 0; j < 4; ++j) {
                acck[i][j] = __builtin_amdgcn_mfma_f32_16x16x32_bf16(af[i], bk[j], acck[i][j], 0, 0, 0);
                accv[i][j] = __builtin_amdgcn_mfma_f32_16x16x32_bf16(af[i], bv[j], accv[i][j], 0, 0, 0);
            }

        // prefetch B(kt+1) into regs (before read-done barrier, before A(kt+2))
        if (kt + 1 < 8) {
            const int k0n = (kt + 1) * 32;
#pragma unroll
            for (int j = 0; j < 4; ++j) {
                bk[j] = *(const bf16x8*)(bkbase + k0n + j * 4096);
                bv[j] = *(const bf16x8*)(bvbase + k0n + j * 4096);
            }
        }

        asm volatile("" ::: "memory");
        __builtin_amdgcn_s_barrier();
        asm volatile("" ::: "memory");
        if (kt + 2 < 8) stage(buf, (kt + 2) * 32);
    }

    const int r0 = (l >> 4) * 4;
    const int cl = l & 15;
    __hip_bfloat16* Kp = Kt + (size_t)z * (HW * C_DIM);
    __hip_bfloat16* Vp = Vt + (size_t)z * (HW * C_DIM);
#pragma unroll
    for (int i = 0; i < 4; ++i) {
        const int row = m0 + wr * 64 + i * 16 + r0;
#pragma unroll
        for (int j = 0; j < 4; ++j) {
            const int col = n0 + wc * 64 + j * 16 + cl;
#pragma unroll
            for (int r = 0; r < 4; ++r) {
                Kp[(size_t)(row + r) * 256 + col] = __float2bfloat16(acck[i][j][r]);
                Vp[(size_t)(row + r) * 256 + col] = __float2bfloat16(accv[i][j][r]);
            }
        }
    }
}

// One thread per (b, w, h): all loads contiguous 64B per head slice.
__global__ __launch_bounds__(256) void attn_kernel(
    const __hip_bfloat16* __restrict__ Qloc,  // [nb][4096][256] bf16
    const __hip_bfloat16* __restrict__ Kt,    // [nb*6][4096][256]
    const __hip_bfloat16* __restrict__ Vt,
    __hip_bfloat16* __restrict__ outT)        // [nb][4096][256]
{
    const int t  = blockIdx.x * 256 + threadIdx.x;
    const int h  = t & 7;
    const int bw = t >> 3;                 // b*4096 + w
    const int b  = bw >> 12;
    const int w  = bw & 4095;
    const float scale = 0.17677669529663687f;  // 32^-0.5

    float q[32];
    const bf16x8* Qp = (const bf16x8*)(Qloc + (size_t)bw * C_DIM + h * 32);
#pragma unroll
    for (int i = 0; i < 4; ++i) {
        bf16x8 qv = Qp[i];
#pragma unroll
        for (int j = 0; j < 8; ++j) q[8 * i + j] = (float)qv[j];
    }

    float s[NV];
#pragma unroll
    for (int v = 0; v < NV; ++v) {
        const bf16x8* Kp = (const bf16x8*)(Kt + ((size_t)(b * NV + v) * HW + w) * C_DIM + h * 32);
        float a = 0.f;
#pragma unroll
        for (int i = 0; i < 4; ++i) {
            bf16x8 kv = Kp[i];
#pragma unroll
            for (int j = 0; j < 8; ++j) a += q[8 * i + j] * (float)kv[j];
        }
        s[v] = a * scale;
    }
    float m = s[0];
#pragma unroll
    for (int v = 1; v < NV; ++v) m = fmaxf(m, s[v]);
    float den = 0.f;
#pragma unroll
    for (int v = 0; v < NV; ++v) { s[v] = __expf(s[v] - m); den += s[v]; }
    const float inv = 1.f / den;

    float o[32];
#pragma unroll
    for (int d = 0; d < 32; ++d) o[d] = 0.f;
#pragma unroll
    for (int v = 0; v < NV; ++v) {
        const float p = s[v] * inv;
        const bf16x8* Vp = (const bf16x8*)(Vt + ((size_t)(b * NV + v) * HW + w) * C_DIM + h * 32);
#pragma unroll
        for (int i = 0; i < 4; ++i) {
            bf16x8 vv = Vp[i];
#pragma unroll
            for (int j = 0; j < 8; ++j) o[8 * i + j] += p * (float)vv[j];
        }
    }
    __hip_bfloat16* op = outT + (size_t)bw * C_DIM + h * 32;
#pragma unroll
    for (int i = 0; i < 4; ++i) {
        bf16x8 ov;
#pragma unroll
        for (int j = 0; j < 8; ++j) ov[j] = (__bf16)o[8 * i + j];
        *(bf16x8*)(op + 8 * i) = ov;
    }
}

extern "C" void kernel_launch(void* const* d_in, const int* in_sizes, int n_in,
                              void* d_out, int out_size, void* d_ws, size_t ws_size,
                              hipStream_t stream)
{
    const float* x  = (const float*)d_in[0];
    const float* Wq = (const float*)d_in[1];
    const float* Wk = (const float*)d_in[2];
    const float* Wv = (const float*)d_in[3];
    const float* Wo = (const float*)d_in[4];
    (void)in_sizes; (void)n_in; (void)out_size; (void)ws_size;

    char* ws = (char*)d_ws;
    const size_t MB = 1024ull * 1024ull;
    const size_t SL = (size_t)HW * C_DIM;                    // 1M elements per slice

    __hip_bfloat16* Wbf   = (__hip_bfloat16*)(ws);           // 512 KB
    __hip_bfloat16* xt    = (__hip_bfloat16*)(ws + 1 * MB);  // 48 MB [4*6][4096][256]
    __hip_bfloat16* Qloc  = (__hip_bfloat16*)(ws + 49 * MB); // 8 MB  [4][4096][256] bf16
    __hip_bfloat16* xbar  = (__hip_bfloat16*)(ws + 57 * MB); // 8 MB  [4][4096][256]
    __hip_bfloat16* attnT = xbar;                            // overlay: xbar dead after Qloc gemm
    __hip_bfloat16* Kt    = (__hip_bfloat16*)(ws + 65 * MB); // 48 MB
    __hip_bfloat16* Vt    = (__hip_bfloat16*)(ws + 113 * MB);// 48 MB

    const __hip_bfloat16* WqB = Wbf;
    const __hip_bfloat16* WkB = Wbf + 65536;
    const __hip_bfloat16* WvB = Wbf + 131072;
    const __hip_bfloat16* WoB = Wbf + 196608;

    convert_weights_kernel<<<dim3(256, 4), 256, 0, stream>>>(Wq, Wk, Wv, Wo, Wbf);
    transpose_mean_kernel<<<dim3(HW / 64, C_DIM / 64, NB), 256, 0, stream>>>(x, xt, xbar);

    // Qloc[b][w][c] bf16 = xbar @ Wq^T
    gemm_generic<1><<<dim3(2, 32, NB), 256, 0, stream>>>(xbar, SL, WqB, 0, Qloc, SL, 256);

    // Kt/Vt fused
    gemm_kv_kernel<<<dim3(2, 32, NB * NV), 256, 0, stream>>>(xt, WkB, WvB, Kt, Vt);

    attn_kernel<<<dim3(NB * 128), 256, 0, stream>>>(Qloc, Kt, Vt, attnT);

    // d_out[b][o][w] fp32 = Wo @ attnT
    gemm_generic<0><<<dim3(32, 2, NB), 256, 0, stream>>>(WoB, 0, attnT, SL, (float*)d_out, SL, 4096);
}

// Round 7
// 98.155 us; speedup vs baseline: 1.6510x; 1.6510x over previous
//
#include <hip/hip_runtime.h>
#include <hip/hip_bf16.h>

// CrossViewAttention: B=4, V=6, C=256, H=W=64 (HW=4096), heads=8, dh=32.
//
// Pipeline (3 launches):
//   1. convert_weights: Wq/Wk/Wv/Wo fp32 -> bf16
//   2. transpose_mean:  x[b][v][c][w] -> xt[b][v][w][c] bf16, xbar[b][w][c] bf16
//   3. mega_kernel: per 64-pixel tile: Q GEMM (from xbar) -> per view: K GEMM,
//      scores, V GEMM, online-softmax PV -> Wo GEMM -> d_out.
//      Kt/Vt/Qloc/attnT intermediates ELIMINATED (saves ~220 MB HBM traffic).

typedef __bf16 bf16x8 __attribute__((ext_vector_type(8)));
typedef float f32x4 __attribute__((ext_vector_type(4)));

#define HW 4096
#define C_DIM 256
#define NV 6
#define NB 4

__global__ __launch_bounds__(256) void convert_weights_kernel(
    const float* __restrict__ Wq, const float* __restrict__ Wk,
    const float* __restrict__ Wv, const float* __restrict__ Wo,
    __hip_bfloat16* __restrict__ out)
{
    const float* srcs[4] = {Wq, Wk, Wv, Wo};
    const int m = blockIdx.y;
    const int i = blockIdx.x * 256 + threadIdx.x;
    out[m * 65536 + i] = __float2bfloat16(srcs[m][i]);
}

// 64x64 tile transpose via LDS; accumulates per-view sum for xbar.
__global__ __launch_bounds__(256) void transpose_mean_kernel(
    const float* __restrict__ x,        // [B][V][C][HW]
    __hip_bfloat16* __restrict__ xt,    // [B][V][HW][C]
    __hip_bfloat16* __restrict__ xbar)  // [B][HW][C]
{
    __shared__ float tile[64][65];
    const int w0 = blockIdx.x * 64;
    const int c0 = blockIdx.y * 64;
    const int b  = blockIdx.z;
    const int t  = threadIdx.x;
    const int li = t & 63;
    const int qi = t >> 6;
    float acc[16];
#pragma unroll
    for (int i = 0; i < 16; ++i) acc[i] = 0.f;

    for (int v = 0; v < NV; ++v) {
        const float* src = x + (((size_t)b * NV + v) * C_DIM + c0) * HW + w0;
#pragma unroll
        for (int i = 0; i < 16; ++i) {
            const int c = qi + 4 * i;
            tile[li][c] = src[(size_t)c * HW + li];
        }
        __syncthreads();
        __hip_bfloat16* dst = xt + (((size_t)b * NV + v) * HW + w0) * C_DIM + c0;
#pragma unroll
        for (int i = 0; i < 16; ++i) {
            const int w = qi + 4 * i;
            const float val = tile[w][li];
            acc[i] += val;
            dst[(size_t)w * C_DIM + li] = __float2bfloat16(val);
        }
        __syncthreads();
    }
    __hip_bfloat16* dbar = xbar + ((size_t)b * HW + w0) * C_DIM + c0;
#pragma unroll
    for (int i = 0; i < 16; ++i) {
        const int w = qi + 4 * i;
        dbar[(size_t)w * C_DIM + li] = __float2bfloat16(acc[i] * (1.f / 6.f));
    }
}

// Mega kernel: 512 threads (8 waves), block owns 64 pixels of batch b.
// GEMM geometry per wave: M=64 (i<4), N=32 (j<2), K=256 (kt<8), 64 MFMA/GEMM.
// A tiles ([kb 0..31][row 0..63][8] bf16, 32 KB) staged via global_load_lds,
// double-buffered across views. B fragments from global (L2-hot weights):
// Wk held in registers across all 6 views, Wq/Wv/Wo streamed with prefetch.
// T tile: [64][257] f32 (odd stride -> 2-way-free scalar LDS reads in
// score/PV phases). Online softmax over views in registers.
__global__ __launch_bounds__(512, 2) void mega_kernel(
    const __hip_bfloat16* __restrict__ xt,    // [B*V][4096][256]
    const __hip_bfloat16* __restrict__ xbar,  // [B][4096][256]
    const __hip_bfloat16* __restrict__ Wq,
    const __hip_bfloat16* __restrict__ Wk,
    const __hip_bfloat16* __restrict__ Wv,
    const __hip_bfloat16* __restrict__ Wo,
    float* __restrict__ out)                  // [B][256][4096]
{
    __shared__ __align__(16) __hip_bfloat16 Abuf[2][16384];  // 2 x 32 KB
    __shared__ float T[64][257];                             // 65.8 KB
    const size_t SL = (size_t)HW * C_DIM;
    const int w0 = blockIdx.x * 64;
    const int b  = blockIdx.y;
    const int t  = threadIdx.x, wv = t >> 6, l = t & 63;
    const int kb_l = l >> 4, rl = l & 15;
    const int px = l, h = wv;                 // softmax-phase mapping

    f32x4 acc[4][2];

    auto zacc = [&]() {
#pragma unroll
        for (int i = 0; i < 4; ++i)
#pragma unroll
            for (int j = 0; j < 2; ++j) {
                acc[i][j][0] = 0.f; acc[i][j][1] = 0.f;
                acc[i][j][2] = 0.f; acc[i][j][3] = 0.f;
            }
    };

    // stage 64x256 bf16 tile into Abuf[buf]: 32 chunks (kb), 4 per wave
    auto stageA = [&](int buf, const __hip_bfloat16* src) {
#pragma unroll
        for (int c2 = 0; c2 < 4; ++c2) {
            const int ch = wv * 4 + c2;       // kb index 0..31
            const __hip_bfloat16* g = src + (size_t)(w0 + l) * 256 + ch * 8;
            __builtin_amdgcn_global_load_lds(
                (const __attribute__((address_space(1))) void*)g,
                (__attribute__((address_space(3))) void*)(&Abuf[buf][ch * 512]),
                16, 0, 0);
        }
    };

    auto ldA = [&](int buf, int kt, bf16x8 af[4]) {
#pragma unroll
        for (int i = 0; i < 4; ++i)
            af[i] = *(const bf16x8*)&Abuf[buf][(kt * 4 + kb_l) * 512 + (i * 16 + rl) * 8];
    };

    auto gemmStream = [&](int buf, const __hip_bfloat16* W) {
        const __hip_bfloat16* wb = W + (size_t)(wv * 32 + rl) * 256 + kb_l * 8;
        bf16x8 bcur[2], bnxt[2];
#pragma unroll
        for (int j = 0; j < 2; ++j) bcur[j] = *(const bf16x8*)(wb + j * 16 * 256);
#pragma unroll
        for (int kt = 0; kt < 8; ++kt) {
            if (kt < 7) {
#pragma unroll
                for (int j = 0; j < 2; ++j)
                    bnxt[j] = *(const bf16x8*)(wb + (kt + 1) * 32 + j * 16 * 256);
            }
            bf16x8 af[4]; ldA(buf, kt, af);
#pragma unroll
            for (int i = 0; i < 4; ++i)
#pragma unroll
                for (int j = 0; j < 2; ++j)
                    acc[i][j] = __builtin_amdgcn_mfma_f32_16x16x32_bf16(af[i], bcur[j], acc[i][j], 0, 0, 0);
            bcur[0] = bnxt[0]; bcur[1] = bnxt[1];
        }
    };

    auto writeT = [&]() {
#pragma unroll
        for (int i = 0; i < 4; ++i)
#pragma unroll
            for (int j = 0; j < 2; ++j)
#pragma unroll
                for (int r = 0; r < 4; ++r)
                    T[i * 16 + (l >> 4) * 4 + r][wv * 32 + j * 16 + rl] = acc[i][j][r];
    };

    // Wk fragments held in registers across all 6 views (64 VGPR)
    bf16x8 bkreg[8][2];
#pragma unroll
    for (int kt = 0; kt < 8; ++kt)
#pragma unroll
        for (int j = 0; j < 2; ++j)
            bkreg[kt][j] = *(const bf16x8*)(Wk + (size_t)(wv * 32 + j * 16 + rl) * 256 + kt * 32 + kb_l * 8);

    auto gemmK = [&](int buf) {
#pragma unroll
        for (int kt = 0; kt < 8; ++kt) {
            bf16x8 af[4]; ldA(buf, kt, af);
#pragma unroll
            for (int i = 0; i < 4; ++i)
#pragma unroll
                for (int j = 0; j < 2; ++j)
                    acc[i][j] = __builtin_amdgcn_mfma_f32_16x16x32_bf16(af[i], bkreg[kt][j], acc[i][j], 0, 0, 0);
        }
    };

    // ---- Q phase ----
    stageA(0, xbar + (size_t)b * SL);
    __syncthreads();                          // S0: xbar tile ready
    zacc();
    gemmStream(0, Wq);
    stageA(1, xt + (size_t)(b * NV) * SL);    // prefetch view 0 (drained at S1)
    writeT();
    __syncthreads();                          // S1: Q in T, xt0 staged

    const float scale = 0.17677669529663687f; // 32^-0.5
    float q[32];
#pragma unroll
    for (int cc = 0; cc < 32; ++cc) q[cc] = T[px][h * 32 + cc] * scale;

    float m = -1e30f, den = 0.f;
    float o[32];
#pragma unroll
    for (int cc = 0; cc < 32; ++cc) o[cc] = 0.f;

    // ---- view loop: K GEMM -> scores -> V GEMM -> online PV ----
    for (int v = 0; v < NV; ++v) {
        const int buf = (v + 1) & 1;          // v0->1, v1->0, ...
        __syncthreads();                      // S2: prior T reads done
        zacc();
        gemmK(buf);
        if (v < NV - 1) stageA(buf ^ 1, xt + (size_t)(b * NV + v + 1) * SL);
        writeT();
        __syncthreads();                      // S3: K in T (and next tile staged)

        float s = 0.f;
#pragma unroll
        for (int cc = 0; cc < 32; ++cc) s += q[cc] * T[px][h * 32 + cc];
        const float mn = fmaxf(m, s);
        const float f  = __expf(m - mn);
        const float e  = __expf(s - mn);
        den = den * f + e;
        m = mn;
#pragma unroll
        for (int cc = 0; cc < 32; ++cc) o[cc] *= f;
        __syncthreads();                      // S4: score reads done, T free

        zacc();
        gemmStream(buf, Wv);
        writeT();
        __syncthreads();                      // S5: V in T
#pragma unroll
        for (int cc = 0; cc < 32; ++cc) o[cc] += e * T[px][h * 32 + cc];
    }

    // ---- epilogue: attn tile -> Abuf[0] (A layout), Wo GEMM, direct stores ----
    const float inv = 1.f / den;
#pragma unroll
    for (int c2 = 0; c2 < 4; ++c2) {
        bf16x8 ov;
#pragma unroll
        for (int k = 0; k < 8; ++k) ov[k] = (__bf16)(o[c2 * 8 + k] * inv);
        *(bf16x8*)&Abuf[0][(h * 4 + c2) * 512 + px * 8] = ov;   // safe: all Abuf[0] reads ended at S5(v=5)
    }
    __syncthreads();                          // S6: attn tile ready
    zacc();
    gemmStream(0, Wo);

    float* op = out + (size_t)b * C_DIM * HW;
#pragma unroll
    for (int i = 0; i < 4; ++i)
#pragma unroll
        for (int j = 0; j < 2; ++j) {
            const int col = wv * 32 + j * 16 + rl;
            *(f32x4*)(op + (size_t)col * HW + w0 + i * 16 + (l >> 4) * 4) = acc[i][j];
        }
}

extern "C" void kernel_launch(void* const* d_in, const int* in_sizes, int n_in,
                              void* d_out, int out_size, void* d_ws, size_t ws_size,
                              hipStream_t stream)
{
    const float* x  = (const float*)d_in[0];
    const float* Wq = (const float*)d_in[1];
    const float* Wk = (const float*)d_in[2];
    const float* Wv = (const float*)d_in[3];
    const float* Wo = (const float*)d_in[4];
    (void)in_sizes; (void)n_in; (void)out_size; (void)ws_size;

    char* ws = (char*)d_ws;
    const size_t MB = 1024ull * 1024ull;
    const size_t SL = (size_t)HW * C_DIM;

    __hip_bfloat16* Wbf  = (__hip_bfloat16*)(ws);            // 512 KB
    __hip_bfloat16* xt   = (__hip_bfloat16*)(ws + 1 * MB);   // 48 MB [4*6][4096][256]
    __hip_bfloat16* xbar = (__hip_bfloat16*)(ws + 49 * MB);  // 8 MB  [4][4096][256]

    const __hip_bfloat16* WqB = Wbf;
    const __hip_bfloat16* WkB = Wbf + 65536;
    const __hip_bfloat16* WvB = Wbf + 131072;
    const __hip_bfloat16* WoB = Wbf + 196608;

    convert_weights_kernel<<<dim3(256, 4), 256, 0, stream>>>(Wq, Wk, Wv, Wo, Wbf);
    transpose_mean_kernel<<<dim3(HW / 64, C_DIM / 64, NB), 256, 0, stream>>>(x, xt, xbar);
    mega_kernel<<<dim3(HW / 64, NB), 512, 0, stream>>>(xt, xbar, WqB, WkB, WvB, WoB, (float*)d_out);
}

// Round 8
// 98.112 us; speedup vs baseline: 1.6517x; 1.0004x over previous
//
#include <hip/hip_runtime.h>
#include <hip/hip_bf16.h>

// CrossViewAttention: B=4, V=6, C=256, H=W=64 (HW=4096), heads=8, dh=32.
//
// Pipeline (3 launches):
//   1. convert_weights: Wq/Wk/Wv/Wo fp32 -> bf16
//   2. transpose_mean:  x[b][v][c][w] -> xt[b][v][w][c] bf16, xbar[b][w][c] bf16
//   3. mega_kernel: per 64-pixel tile: Q GEMM (from xbar) -> per view: K GEMM,
//      scores, V GEMM, online-softmax PV -> Wo GEMM -> d_out.
//      Kt/Vt/Qloc/attnT intermediates ELIMINATED (saves ~220 MB HBM traffic).

typedef __bf16 bf16x8 __attribute__((ext_vector_type(8)));
typedef float f32x4 __attribute__((ext_vector_type(4)));

#define HW 4096
#define C_DIM 256
#define NV 6
#define NB 4

__global__ __launch_bounds__(256) void convert_weights_kernel(
    const float* __restrict__ Wq, const float* __restrict__ Wk,
    const float* __restrict__ Wv, const float* __restrict__ Wo,
    __hip_bfloat16* __restrict__ out)
{
    const float* srcs[4] = {Wq, Wk, Wv, Wo};
    const int m = blockIdx.y;
    const int i = blockIdx.x * 256 + threadIdx.x;
    out[m * 65536 + i] = __float2bfloat16(srcs[m][i]);
}

// 64x64 tile transpose via LDS; accumulates per-view sum for xbar.
__global__ __launch_bounds__(256) void transpose_mean_kernel(
    const float* __restrict__ x,        // [B][V][C][HW]
    __hip_bfloat16* __restrict__ xt,    // [B][V][HW][C]
    __hip_bfloat16* __restrict__ xbar)  // [B][HW][C]
{
    __shared__ float tile[64][65];
    const int w0 = blockIdx.x * 64;
    const int c0 = blockIdx.y * 64;
    const int b  = blockIdx.z;
    const int t  = threadIdx.x;
    const int li = t & 63;
    const int qi = t >> 6;
    float acc[16];
#pragma unroll
    for (int i = 0; i < 16; ++i) acc[i] = 0.f;

    for (int v = 0; v < NV; ++v) {
        const float* src = x + (((size_t)b * NV + v) * C_DIM + c0) * HW + w0;
#pragma unroll
        for (int i = 0; i < 16; ++i) {
            const int c = qi + 4 * i;
            tile[li][c] = src[(size_t)c * HW + li];
        }
        __syncthreads();
        __hip_bfloat16* dst = xt + (((size_t)b * NV + v) * HW + w0) * C_DIM + c0;
#pragma unroll
        for (int i = 0; i < 16; ++i) {
            const int w = qi + 4 * i;
            const float val = tile[w][li];
            acc[i] += val;
            dst[(size_t)w * C_DIM + li] = __float2bfloat16(val);
        }
        __syncthreads();
    }
    __hip_bfloat16* dbar = xbar + ((size_t)b * HW + w0) * C_DIM + c0;
#pragma unroll
    for (int i = 0; i < 16; ++i) {
        const int w = qi + 4 * i;
        dbar[(size_t)w * C_DIM + li] = __float2bfloat16(acc[i] * (1.f / 6.f));
    }
}

// Mega kernel: 512 threads (8 waves), block owns 64 pixels of batch b.
// GEMM geometry per wave: M=64 (i<4), N=32 (j<2), K=256 (kt<8), 64 MFMA/GEMM.
// A tiles ([kb 0..31][row 0..63][8] bf16, 32 KB) staged via global_load_lds,
// double-buffered across views. B fragments from global (L2-hot weights):
// Wk held in registers across all 6 views, Wq/Wv/Wo streamed with prefetch.
// T tile: [64][257] f32 (odd stride -> 2-way-free scalar LDS reads in
// score/PV phases). Online softmax over views in registers.
__global__ __launch_bounds__(512, 2) void mega_kernel(
    const __hip_bfloat16* __restrict__ xt,    // [B*V][4096][256]
    const __hip_bfloat16* __restrict__ xbar,  // [B][4096][256]
    const __hip_bfloat16* __restrict__ Wq,
    const __hip_bfloat16* __restrict__ Wk,
    const __hip_bfloat16* __restrict__ Wv,
    const __hip_bfloat16* __restrict__ Wo,
    float* __restrict__ out)                  // [B][256][4096]
{
    __shared__ __align__(16) __hip_bfloat16 Abuf[2][16384];  // 2 x 32 KB
    __shared__ float T[64][257];                             // 65.8 KB
    const size_t SL = (size_t)HW * C_DIM;
    const int w0 = blockIdx.x * 64;
    const int b  = blockIdx.y;
    const int t  = threadIdx.x, wv = t >> 6, l = t & 63;
    const int kb_l = l >> 4, rl = l & 15;
    const int px = l, h = wv;                 // softmax-phase mapping

    f32x4 acc[4][2];

    auto zacc = [&]() {
#pragma unroll
        for (int i = 0; i < 4; ++i)
#pragma unroll
            for (int j = 0; j < 2; ++j) {
                acc[i][j][0] = 0.f; acc[i][j][1] = 0.f;
                acc[i][j][2] = 0.f; acc[i][j][3] = 0.f;
            }
    };

    // stage 64x256 bf16 tile into Abuf[buf]: 32 chunks (kb), 4 per wave
    auto stageA = [&](int buf, const __hip_bfloat16* src) {
#pragma unroll
        for (int c2 = 0; c2 < 4; ++c2) {
            const int ch = wv * 4 + c2;       // kb index 0..31
            const __hip_bfloat16* g = src + (size_t)(w0 + l) * 256 + ch * 8;
            __builtin_amdgcn_global_load_lds(
                (const __attribute__((address_space(1))) void*)g,
                (__attribute__((address_space(3))) void*)(&Abuf[buf][ch * 512]),
                16, 0, 0);
        }
    };

    auto ldA = [&](int buf, int kt, bf16x8 af[4]) {
#pragma unroll
        for (int i = 0; i < 4; ++i)
            af[i] = *(const bf16x8*)&Abuf[buf][(kt * 4 + kb_l) * 512 + (i * 16 + rl) * 8];
    };

    auto gemmStream = [&](int buf, const __hip_bfloat16* W) {
        const __hip_bfloat16* wb = W + (size_t)(wv * 32 + rl) * 256 + kb_l * 8;
        bf16x8 bcur[2], bnxt[2];
#pragma unroll
        for (int j = 0; j < 2; ++j) bcur[j] = *(const bf16x8*)(wb + j * 16 * 256);
#pragma unroll
        for (int kt = 0; kt < 8; ++kt) {
            if (kt < 7) {
#pragma unroll
                for (int j = 0; j < 2; ++j)
                    bnxt[j] = *(const bf16x8*)(wb + (kt + 1) * 32 + j * 16 * 256);
            }
            bf16x8 af[4]; ldA(buf, kt, af);
#pragma unroll
            for (int i = 0; i < 4; ++i)
#pragma unroll
                for (int j = 0; j < 2; ++j)
                    acc[i][j] = __builtin_amdgcn_mfma_f32_16x16x32_bf16(af[i], bcur[j], acc[i][j], 0, 0, 0);
            bcur[0] = bnxt[0]; bcur[1] = bnxt[1];
        }
    };

    auto writeT = [&]() {
#pragma unroll
        for (int i = 0; i < 4; ++i)
#pragma unroll
            for (int j = 0; j < 2; ++j)
#pragma unroll
                for (int r = 0; r < 4; ++r)
                    T[i * 16 + (l >> 4) * 4 + r][wv * 32 + j * 16 + rl] = acc[i][j][r];
    };

    // Wk fragments held in registers across all 6 views (64 VGPR)
    bf16x8 bkreg[8][2];
#pragma unroll
    for (int kt = 0; kt < 8; ++kt)
#pragma unroll
        for (int j = 0; j < 2; ++j)
            bkreg[kt][j] = *(const bf16x8*)(Wk + (size_t)(wv * 32 + j * 16 + rl) * 256 + kt * 32 + kb_l * 8);

    auto gemmK = [&](int buf) {
#pragma unroll
        for (int kt = 0; kt < 8; ++kt) {
            bf16x8 af[4]; ldA(buf, kt, af);
#pragma unroll
            for (int i = 0; i < 4; ++i)
#pragma unroll
                for (int j = 0; j < 2; ++j)
                    acc[i][j] = __builtin_amdgcn_mfma_f32_16x16x32_bf16(af[i], bkreg[kt][j], acc[i][j], 0, 0, 0);
        }
    };

    // ---- Q phase ----
    stageA(0, xbar + (size_t)b * SL);
    __syncthreads();                          // S0: xbar tile ready
    zacc();
    gemmStream(0, Wq);
    stageA(1, xt + (size_t)(b * NV) * SL);    // prefetch view 0 (drained at S1)
    writeT();
    __syncthreads();                          // S1: Q in T, xt0 staged

    const float scale = 0.17677669529663687f; // 32^-0.5
    float q[32];
#pragma unroll
    for (int cc = 0; cc < 32; ++cc) q[cc] = T[px][h * 32 + cc] * scale;

    float m = -1e30f, den = 0.f;
    float o[32];
#pragma unroll
    for (int cc = 0; cc < 32; ++cc) o[cc] = 0.f;

    // ---- view loop: K GEMM -> scores -> V GEMM -> online PV ----
    for (int v = 0; v < NV; ++v) {
        const int buf = (v + 1) & 1;          // v0->1, v1->0, ...
        __syncthreads();                      // S2: prior T reads done
        zacc();
        gemmK(buf);
        if (v < NV - 1) stageA(buf ^ 1, xt + (size_t)(b * NV + v + 1) * SL);
        writeT();
        __syncthreads();                      // S3: K in T (and next tile staged)

        float s = 0.f;
#pragma unroll
        for (int cc = 0; cc < 32; ++cc) s += q[cc] * T[px][h * 32 + cc];
        const float mn = fmaxf(m, s);
        const float f  = __expf(m - mn);
        const float e  = __expf(s - mn);
        den = den * f + e;
        m = mn;
#pragma unroll
        for (int cc = 0; cc < 32; ++cc) o[cc] *= f;
        __syncthreads();                      // S4: score reads done, T free

        zacc();
        gemmStream(buf, Wv);
        writeT();
        __syncthreads();                      // S5: V in T
#pragma unroll
        for (int cc = 0; cc < 32; ++cc) o[cc] += e * T[px][h * 32 + cc];
    }

    // ---- epilogue: attn tile -> Abuf[0] (A layout), Wo GEMM, direct stores ----
    const float inv = 1.f / den;
#pragma unroll
    for (int c2 = 0; c2 < 4; ++c2) {
        bf16x8 ov;
#pragma unroll
        for (int k = 0; k < 8; ++k) ov[k] = (__bf16)(o[c2 * 8 + k] * inv);
        *(bf16x8*)&Abuf[0][(h * 4 + c2) * 512 + px * 8] = ov;   // safe: all Abuf[0] reads ended at S5(v=5)
    }
    __syncthreads();                          // S6: attn tile ready
    zacc();
    gemmStream(0, Wo);

    float* op = out + (size_t)b * C_DIM * HW;
#pragma unroll
    for (int i = 0; i < 4; ++i)
#pragma unroll
        for (int j = 0; j < 2; ++j) {
            const int col = wv * 32 + j * 16 + rl;
            *(f32x4*)(op + (size_t)col * HW + w0 + i * 16 + (l >> 4) * 4) = acc[i][j];
        }
}

extern "C" void kernel_launch(void* const* d_in, const int* in_sizes, int n_in,
                              void* d_out, int out_size, void* d_ws, size_t ws_size,
                              hipStream_t stream)
{
    const float* x  = (const float*)d_in[0];
    const float* Wq = (const float*)d_in[1];
    const float* Wk = (const float*)d_in[2];
    const float* Wv = (const float*)d_in[3];
    const float* Wo = (const float*)d_in[4];
    (void)in_sizes; (void)n_in; (void)out_size; (void)ws_size;

    char* ws = (char*)d_ws;
    const size_t MB = 1024ull * 1024ull;
    const size_t SL = (size_t)HW * C_DIM;

    __hip_bfloat16* Wbf  = (__hip_bfloat16*)(ws);            // 512 KB
    __hip_bfloat16* xt   = (__hip_bfloat16*)(ws + 1 * MB);   // 48 MB [4*6][4096][256]
    __hip_bfloat16* xbar = (__hip_bfloat16*)(ws + 49 * MB);  // 8 MB  [4][4096][256]

    const __hip_bfloat16* WqB = Wbf;
    const __hip_bfloat16* WkB = Wbf + 65536;
    const __hip_bfloat16* WvB = Wbf + 131072;
    const __hip_bfloat16* WoB = Wbf + 196608;

    convert_weights_kernel<<<dim3(256, 4), 256, 0, stream>>>(Wq, Wk, Wv, Wo, Wbf);
    transpose_mean_kernel<<<dim3(HW / 64, C_DIM / 64, NB), 256, 0, stream>>>(x, xt, xbar);
    mega_kernel<<<dim3(HW / 64, NB), 512, 0, stream>>>(xt, xbar, WqB, WkB, WvB, WoB, (float*)d_out);
}

// Round 9
// 97.889 us; speedup vs baseline: 1.6555x; 1.0023x over previous
//
#include <hip/hip_runtime.h>
#include <hip/hip_bf16.h>

// CrossViewAttention: B=4, V=6, C=256, H=W=64 (HW=4096), heads=8, dh=32.
//
// Pipeline (3 launches):
//   1. convert_weights: Wq/Wk/Wv/Wo fp32 -> bf16
//   2. transpose_mean:  x[b][v][c][w] -> xt[b][v][w][c] bf16, xbar[b][w][c] bf16
//   3. mega_kernel: per 64-pixel tile: Q GEMM (from xbar) -> per view: K GEMM,
//      scores, V GEMM, online-softmax PV -> Wo GEMM -> d_out.
//      Kt/Vt/Qloc/attnT intermediates ELIMINATED (saves ~220 MB HBM traffic).

typedef __bf16 bf16x8 __attribute__((ext_vector_type(8)));
typedef float f32x4 __attribute__((ext_vector_type(4)));

#define HW 4096
#define C_DIM 256
#define NV 6
#define NB 4

__global__ __launch_bounds__(256) void convert_weights_kernel(
    const float* __restrict__ Wq, const float* __restrict__ Wk,
    const float* __restrict__ Wv, const float* __restrict__ Wo,
    __hip_bfloat16* __restrict__ out)
{
    const float* srcs[4] = {Wq, Wk, Wv, Wo};
    const int m = blockIdx.y;
    const int i = blockIdx.x * 256 + threadIdx.x;
    out[m * 65536 + i] = __float2bfloat16(srcs[m][i]);
}

// 64x64 tile transpose via LDS; accumulates per-view sum for xbar.
__global__ __launch_bounds__(256) void transpose_mean_kernel(
    const float* __restrict__ x,        // [B][V][C][HW]
    __hip_bfloat16* __restrict__ xt,    // [B][V][HW][C]
    __hip_bfloat16* __restrict__ xbar)  // [B][HW][C]
{
    __shared__ float tile[64][65];
    const int w0 = blockIdx.x * 64;
    const int c0 = blockIdx.y * 64;
    const int b  = blockIdx.z;
    const int t  = threadIdx.x;
    const int li = t & 63;
    const int qi = t >> 6;
    float acc[16];
#pragma unroll
    for (int i = 0; i < 16; ++i) acc[i] = 0.f;

    for (int v = 0; v < NV; ++v) {
        const float* src = x + (((size_t)b * NV + v) * C_DIM + c0) * HW + w0;
#pragma unroll
        for (int i = 0; i < 16; ++i) {
            const int c = qi + 4 * i;
            tile[li][c] = src[(size_t)c * HW + li];
        }
        __syncthreads();
        __hip_bfloat16* dst = xt + (((size_t)b * NV + v) * HW + w0) * C_DIM + c0;
#pragma unroll
        for (int i = 0; i < 16; ++i) {
            const int w = qi + 4 * i;
            const float val = tile[w][li];
            acc[i] += val;
            dst[(size_t)w * C_DIM + li] = __float2bfloat16(val);
        }
        __syncthreads();
    }
    __hip_bfloat16* dbar = xbar + ((size_t)b * HW + w0) * C_DIM + c0;
#pragma unroll
    for (int i = 0; i < 16; ++i) {
        const int w = qi + 4 * i;
        dbar[(size_t)w * C_DIM + li] = __float2bfloat16(acc[i] * (1.f / 6.f));
    }
}

// Mega kernel: 512 threads (8 waves), block owns 64 pixels of batch b.
// GEMM geometry per wave: M=64 (i<4), N=32 (j<2), K=256 (kt<8), 64 MFMA/GEMM.
// A tiles ([kb 0..31][row 0..63][8] bf16, 32 KB) staged via global_load_lds,
// double-buffered across views. B fragments from global (L2-hot weights):
// Wk held in registers across all 6 views, Wq/Wv/Wo streamed with prefetch.
// T tile: [64][257] f32 (odd stride -> 2-way-free scalar LDS reads in
// score/PV phases). Online softmax over views in registers.
__global__ __launch_bounds__(512, 2) void mega_kernel(
    const __hip_bfloat16* __restrict__ xt,    // [B*V][4096][256]
    const __hip_bfloat16* __restrict__ xbar,  // [B][4096][256]
    const __hip_bfloat16* __restrict__ Wq,
    const __hip_bfloat16* __restrict__ Wk,
    const __hip_bfloat16* __restrict__ Wv,
    const __hip_bfloat16* __restrict__ Wo,
    float* __restrict__ out)                  // [B][256][4096]
{
    __shared__ __align__(16) __hip_bfloat16 Abuf[2][16384];  // 2 x 32 KB
    __shared__ float T[64][257];                             // 65.8 KB
    const size_t SL = (size_t)HW * C_DIM;
    const int w0 = blockIdx.x * 64;
    const int b  = blockIdx.y;
    const int t  = threadIdx.x, wv = t >> 6, l = t & 63;
    const int kb_l = l >> 4, rl = l & 15;
    const int px = l, h = wv;                 // softmax-phase mapping

    f32x4 acc[4][2];

    auto zacc = [&]() {
#pragma unroll
        for (int i = 0; i < 4; ++i)
#pragma unroll
            for (int j = 0; j < 2; ++j) {
                acc[i][j][0] = 0.f; acc[i][j][1] = 0.f;
                acc[i][j][2] = 0.f; acc[i][j][3] = 0.f;
            }
    };

    // stage 64x256 bf16 tile into Abuf[buf]: 32 chunks (kb), 4 per wave
    auto stageA = [&](int buf, const __hip_bfloat16* src) {
#pragma unroll
        for (int c2 = 0; c2 < 4; ++c2) {
            const int ch = wv * 4 + c2;       // kb index 0..31
            const __hip_bfloat16* g = src + (size_t)(w0 + l) * 256 + ch * 8;
            __builtin_amdgcn_global_load_lds(
                (const __attribute__((address_space(1))) void*)g,
                (__attribute__((address_space(3))) void*)(&Abuf[buf][ch * 512]),
                16, 0, 0);
        }
    };

    auto ldA = [&](int buf, int kt, bf16x8 af[4]) {
#pragma unroll
        for (int i = 0; i < 4; ++i)
            af[i] = *(const bf16x8*)&Abuf[buf][(kt * 4 + kb_l) * 512 + (i * 16 + rl) * 8];
    };

    auto gemmStream = [&](int buf, const __hip_bfloat16* W) {
        const __hip_bfloat16* wb = W + (size_t)(wv * 32 + rl) * 256 + kb_l * 8;
        bf16x8 bcur[2], bnxt[2];
#pragma unroll
        for (int j = 0; j < 2; ++j) bcur[j] = *(const bf16x8*)(wb + j * 16 * 256);
#pragma unroll
        for (int kt = 0; kt < 8; ++kt) {
            if (kt < 7) {
#pragma unroll
                for (int j = 0; j < 2; ++j)
                    bnxt[j] = *(const bf16x8*)(wb + (kt + 1) * 32 + j * 16 * 256);
            }
            bf16x8 af[4]; ldA(buf, kt, af);
#pragma unroll
            for (int i = 0; i < 4; ++i)
#pragma unroll
                for (int j = 0; j < 2; ++j)
                    acc[i][j] = __builtin_amdgcn_mfma_f32_16x16x32_bf16(af[i], bcur[j], acc[i][j], 0, 0, 0);
            bcur[0] = bnxt[0]; bcur[1] = bnxt[1];
        }
    };

    auto writeT = [&]() {
#pragma unroll
        for (int i = 0; i < 4; ++i)
#pragma unroll
            for (int j = 0; j < 2; ++j)
#pragma unroll
                for (int r = 0; r < 4; ++r)
                    T[i * 16 + (l >> 4) * 4 + r][wv * 32 + j * 16 + rl] = acc[i][j][r];
    };

    // Wk fragments held in registers across all 6 views (64 VGPR)
    bf16x8 bkreg[8][2];
#pragma unroll
    for (int kt = 0; kt < 8; ++kt)
#pragma unroll
        for (int j = 0; j < 2; ++j)
            bkreg[kt][j] = *(const bf16x8*)(Wk + (size_t)(wv * 32 + j * 16 + rl) * 256 + kt * 32 + kb_l * 8);

    auto gemmK = [&](int buf) {
#pragma unroll
        for (int kt = 0; kt < 8; ++kt) {
            bf16x8 af[4]; ldA(buf, kt, af);
#pragma unroll
            for (int i = 0; i < 4; ++i)
#pragma unroll
                for (int j = 0; j < 2; ++j)
                    acc[i][j] = __builtin_amdgcn_mfma_f32_16x16x32_bf16(af[i], bkreg[kt][j], acc[i][j], 0, 0, 0);
        }
    };

    // ---- Q phase ----
    stageA(0, xbar + (size_t)b * SL);
    __syncthreads();                          // S0: xbar tile ready
    zacc();
    gemmStream(0, Wq);
    stageA(1, xt + (size_t)(b * NV) * SL);    // prefetch view 0 (drained at S1)
    writeT();
    __syncthreads();                          // S1: Q in T, xt0 staged

    const float scale = 0.17677669529663687f; // 32^-0.5
    float q[32];
#pragma unroll
    for (int cc = 0; cc < 32; ++cc) q[cc] = T[px][h * 32 + cc] * scale;

    float m = -1e30f, den = 0.f;
    float o[32];
#pragma unroll
    for (int cc = 0; cc < 32; ++cc) o[cc] = 0.f;

    // ---- view loop: K GEMM -> scores -> V GEMM -> online PV ----
    for (int v = 0; v < NV; ++v) {
        const int buf = (v + 1) & 1;          // v0->1, v1->0, ...
        __syncthreads();                      // S2: prior T reads done
        zacc();
        gemmK(buf);
        if (v < NV - 1) stageA(buf ^ 1, xt + (size_t)(b * NV + v + 1) * SL);
        writeT();
        __syncthreads();                      // S3: K in T (and next tile staged)

        float s = 0.f;
#pragma unroll
        for (int cc = 0; cc < 32; ++cc) s += q[cc] * T[px][h * 32 + cc];
        const float mn = fmaxf(m, s);
        const float f  = __expf(m - mn);
        const float e  = __expf(s - mn);
        den = den * f + e;
        m = mn;
#pragma unroll
        for (int cc = 0; cc < 32; ++cc) o[cc] *= f;
        __syncthreads();                      // S4: score reads done, T free

        zacc();
        gemmStream(buf, Wv);
        writeT();
        __syncthreads();                      // S5: V in T
#pragma unroll
        for (int cc = 0; cc < 32; ++cc) o[cc] += e * T[px][h * 32 + cc];
    }

    // ---- epilogue: attn tile -> Abuf[0] (A layout), Wo GEMM, direct stores ----
    const float inv = 1.f / den;
#pragma unroll
    for (int c2 = 0; c2 < 4; ++c2) {
        bf16x8 ov;
#pragma unroll
        for (int k = 0; k < 8; ++k) ov[k] = (__bf16)(o[c2 * 8 + k] * inv);
        *(bf16x8*)&Abuf[0][(h * 4 + c2) * 512 + px * 8] = ov;   // safe: all Abuf[0] reads ended at S5(v=5)
    }
    __syncthreads();                          // S6: attn tile ready
    zacc();
    gemmStream(0, Wo);

    float* op = out + (size_t)b * C_DIM * HW;
#pragma unroll
    for (int i = 0; i < 4; ++i)
#pragma unroll
        for (int j = 0; j < 2; ++j) {
            const int col = wv * 32 + j * 16 + rl;
            *(f32x4*)(op + (size_t)col * HW + w0 + i * 16 + (l >> 4) * 4) = acc[i][j];
        }
}

extern "C" void kernel_launch(void* const* d_in, const int* in_sizes, int n_in,
                              void* d_out, int out_size, void* d_ws, size_t ws_size,
                              hipStream_t stream)
{
    const float* x  = (const float*)d_in[0];
    const float* Wq = (const float*)d_in[1];
    const float* Wk = (const float*)d_in[2];
    const float* Wv = (const float*)d_in[3];
    const float* Wo = (const float*)d_in[4];
    (void)in_sizes; (void)n_in; (void)out_size; (void)ws_size;

    char* ws = (char*)d_ws;
    const size_t MB = 1024ull * 1024ull;
    const size_t SL = (size_t)HW * C_DIM;

    __hip_bfloat16* Wbf  = (__hip_bfloat16*)(ws);            // 512 KB
    __hip_bfloat16* xt   = (__hip_bfloat16*)(ws + 1 * MB);   // 48 MB [4*6][4096][256]
    __hip_bfloat16* xbar = (__hip_bfloat16*)(ws + 49 * MB);  // 8 MB  [4][4096][256]

    const __hip_bfloat16* WqB = Wbf;
    const __hip_bfloat16* WkB = Wbf + 65536;
    const __hip_bfloat16* WvB = Wbf + 131072;
    const __hip_bfloat16* WoB = Wbf + 196608;

    convert_weights_kernel<<<dim3(256, 4), 256, 0, stream>>>(Wq, Wk, Wv, Wo, Wbf);
    transpose_mean_kernel<<<dim3(HW / 64, C_DIM / 64, NB), 256, 0, stream>>>(x, xt, xbar);
    mega_kernel<<<dim3(HW / 64, NB), 512, 0, stream>>>(xt, xbar, WqB, WkB, WvB, WoB, (float*)d_out);
}

// Round 10
// 96.611 us; speedup vs baseline: 1.6774x; 1.0132x over previous
//
#include <hip/hip_runtime.h>
#include <hip/hip_bf16.h>

// CrossViewAttention: B=4, V=6, C=256, H=W=64 (HW=4096), heads=8, dh=32.
//
// Pipeline (3 launches):
//   1. convert_weights: Wq/Wk/Wv/Wo fp32 -> bf16
//   2. transpose_mean:  x[b][v][c][w] -> xt[b][v][w][c] bf16, xbar[b][w][c] bf16
//   3. mega_kernel: per 64-pixel tile: Q GEMM -> per view {K GEMM, scores,
//      V GEMM, online-softmax PV} -> Wo GEMM -> d_out.
//      Round-10 changes: Wk+Wv fragments RESIDENT in VGPRs across views
//      (no per-K-step L2 loads on the critical path); Wq/Wo preloaded as
//      batches far ahead of use; T tile col-major [256][68] f32 so
//      accumulator spill is 8x ds_write_b128 instead of 32 scalar writes;
//      next-view stage issued before gemmK (HBM latency hidden).

typedef __bf16 bf16x8 __attribute__((ext_vector_type(8)));
typedef float f32x4 __attribute__((ext_vector_type(4)));

#define HW 4096
#define C_DIM 256
#define NV 6
#define NB 4

__global__ __launch_bounds__(256) void convert_weights_kernel(
    const float* __restrict__ Wq, const float* __restrict__ Wk,
    const float* __restrict__ Wv, const float* __restrict__ Wo,
    __hip_bfloat16* __restrict__ out)
{
    const float* srcs[4] = {Wq, Wk, Wv, Wo};
    const int m = blockIdx.y;
    const int i = blockIdx.x * 256 + threadIdx.x;
    out[m * 65536 + i] = __float2bfloat16(srcs[m][i]);
}

// 64x64 tile transpose via LDS; accumulates per-view sum for xbar.
__global__ __launch_bounds__(256) void transpose_mean_kernel(
    const float* __restrict__ x,        // [B][V][C][HW]
    __hip_bfloat16* __restrict__ xt,    // [B][V][HW][C]
    __hip_bfloat16* __restrict__ xbar)  // [B][HW][C]
{
    __shared__ float tile[64][65];
    const int w0 = blockIdx.x * 64;
    const int c0 = blockIdx.y * 64;
    const int b  = blockIdx.z;
    const int t  = threadIdx.x;
    const int li = t & 63;
    const int qi = t >> 6;
    float acc[16];
#pragma unroll
    for (int i = 0; i < 16; ++i) acc[i] = 0.f;

    for (int v = 0; v < NV; ++v) {
        const float* src = x + (((size_t)b * NV + v) * C_DIM + c0) * HW + w0;
#pragma unroll
        for (int i = 0; i < 16; ++i) {
            const int c = qi + 4 * i;
            tile[li][c] = src[(size_t)c * HW + li];
        }
        __syncthreads();
        __hip_bfloat16* dst = xt + (((size_t)b * NV + v) * HW + w0) * C_DIM + c0;
#pragma unroll
        for (int i = 0; i < 16; ++i) {
            const int w = qi + 4 * i;
            const float val = tile[w][li];
            acc[i] += val;
            dst[(size_t)w * C_DIM + li] = __float2bfloat16(val);
        }
        __syncthreads();
    }
    __hip_bfloat16* dbar = xbar + ((size_t)b * HW + w0) * C_DIM + c0;
#pragma unroll
    for (int i = 0; i < 16; ++i) {
        const int w = qi + 4 * i;
        dbar[(size_t)w * C_DIM + li] = __float2bfloat16(acc[i] * (1.f / 6.f));
    }
}

// Mega kernel: 512 threads (8 waves), block owns 64 pixels of batch b.
// Per-wave GEMM: M=64 (i<4), N=32 (j<2), K=256 (kt<8), 64 MFMA.
// LDS: Abuf 2x32KB (A tiles, [kb 0..31][row 0..63][8] bf16) + T2[256][68] f32
// (col-major C tile; 68 pad -> 16B-aligned f32x4 rows, ~2-way bank alias).
__global__ __launch_bounds__(512, 1) void mega_kernel(
    const __hip_bfloat16* __restrict__ xt,    // [B*V][4096][256]
    const __hip_bfloat16* __restrict__ xbar,  // [B][4096][256]
    const __hip_bfloat16* __restrict__ Wq,
    const __hip_bfloat16* __restrict__ Wk,
    const __hip_bfloat16* __restrict__ Wv,
    const __hip_bfloat16* __restrict__ Wo,
    float* __restrict__ out)                  // [B][256][4096]
{
    __shared__ __align__(16) __hip_bfloat16 Abuf[2][16384];  // 64 KB
    __shared__ __align__(16) float T2[256][68];              // 68 KB
    const size_t SL = (size_t)HW * C_DIM;
    const int w0 = blockIdx.x * 64;
    const int b  = blockIdx.y;
    const int t  = threadIdx.x, wv = t >> 6, l = t & 63;
    const int kb_l = l >> 4, rl = l & 15, lq = l >> 4;
    const int px = l, h = wv;                 // softmax-phase mapping

    f32x4 acc[4][2];
    auto zacc = [&]() {
#pragma unroll
        for (int i = 0; i < 4; ++i)
#pragma unroll
            for (int j = 0; j < 2; ++j) {
                acc[i][j][0] = 0.f; acc[i][j][1] = 0.f;
                acc[i][j][2] = 0.f; acc[i][j][3] = 0.f;
            }
    };

    // stage 64x256 bf16 tile into Abuf[buf]: 32 chunks, 4 per wave
    auto stageA = [&](int buf, const __hip_bfloat16* src) {
#pragma unroll
        for (int c2 = 0; c2 < 4; ++c2) {
            const int ch = wv * 4 + c2;       // kb index 0..31
            const __hip_bfloat16* g = src + (size_t)(w0 + l) * 256 + ch * 8;
            __builtin_amdgcn_global_load_lds(
                (const __attribute__((address_space(1))) void*)g,
                (__attribute__((address_space(3))) void*)(&Abuf[buf][ch * 512]),
                16, 0, 0);
        }
    };

    // load all 16 B-fragments of a weight matrix for this wave's 32 cols
    auto preloadW = [&](const __hip_bfloat16* W, bf16x8 (&fr)[8][2]) {
#pragma unroll
        for (int kt = 0; kt < 8; ++kt)
#pragma unroll
            for (int j = 0; j < 2; ++j)
                fr[kt][j] = *(const bf16x8*)(W + (size_t)(wv * 32 + j * 16 + rl) * 256 + kt * 32 + kb_l * 8);
    };

    // GEMM with register-resident B fragments (pure LDS + MFMA)
    auto gemmFrags = [&](int buf, const bf16x8 (&fr)[8][2]) {
#pragma unroll
        for (int kt = 0; kt < 8; ++kt) {
            bf16x8 af[4];
#pragma unroll
            for (int i = 0; i < 4; ++i)
                af[i] = *(const bf16x8*)&Abuf[buf][(kt * 4 + kb_l) * 512 + (i * 16 + rl) * 8];
#pragma unroll
            for (int i = 0; i < 4; ++i)
#pragma unroll
                for (int j = 0; j < 2; ++j)
                    acc[i][j] = __builtin_amdgcn_mfma_f32_16x16x32_bf16(af[i], fr[kt][j], acc[i][j], 0, 0, 0);
        }
    };

    // acc -> T2 (col-major): 8x ds_write_b128
    auto writeT2 = [&]() {
#pragma unroll
        for (int i = 0; i < 4; ++i)
#pragma unroll
            for (int j = 0; j < 2; ++j)
                *(f32x4*)&T2[wv * 32 + j * 16 + rl][i * 16 + lq * 4] = acc[i][j];
    };

    bf16x8 bkreg[8][2], bvreg[8][2];

    // ---- prologue + Q phase ----
    stageA(0, xbar + (size_t)b * SL);
    bf16x8 wqf[8][2];
    preloadW(Wq, wqf);
    preloadW(Wk, bkreg);
    __syncthreads();                          // S0: xbar tile ready
    zacc();
    gemmFrags(0, wqf);
    stageA(1, xt + (size_t)(b * NV) * SL);    // view 0 tile (drains at S1)
    preloadW(Wv, bvreg);                      // far ahead of first gemmV
    writeT2();
    __syncthreads();                          // S1: Q in T2, xt0 staged

    // q packed bf16 (16 VGPR), scale absorbed
    const float scale = 0.17677669529663687f; // 32^-0.5
    bf16x8 qbf[4];
#pragma unroll
    for (int i = 0; i < 4; ++i)
#pragma unroll
        for (int j = 0; j < 8; ++j)
            qbf[i][j] = (__bf16)(T2[h * 32 + i * 8 + j][px] * scale);

    float m = -1e30f, den = 0.f;
    float o[32];
#pragma unroll
    for (int cc = 0; cc < 32; ++cc) o[cc] = 0.f;

    bf16x8 wof[8][2];

    // ---- view loop ----
    for (int v = 0; v < NV; ++v) {
        const int buf = (v + 1) & 1;          // v0->1, v1->0, ...
        __syncthreads();                      // S2: prior T2 reads done
        if (v < NV - 1) stageA(buf ^ 1, xt + (size_t)(b * NV + v + 1) * SL);
        zacc();
        gemmFrags(buf, bkreg);
        writeT2();
        __syncthreads();                      // S3: K in T2; next tile staged

        float s = 0.f;
#pragma unroll
        for (int i = 0; i < 4; ++i)
#pragma unroll
            for (int j = 0; j < 8; ++j)
                s += (float)qbf[i][j] * T2[h * 32 + i * 8 + j][px];
        const float mn = fmaxf(m, s);
        const float f  = __expf(m - mn);
        const float e  = __expf(s - mn);
        den = den * f + e;
        m = mn;
#pragma unroll
        for (int cc = 0; cc < 32; ++cc) o[cc] *= f;
        __syncthreads();                      // S4: score reads done, T2 free

        zacc();
        gemmFrags(buf, bvreg);
        if (v == NV - 1) preloadW(Wo, wof);   // after last bk/bv use
        writeT2();
        __syncthreads();                      // S5: V in T2
#pragma unroll
        for (int cc = 0; cc < 32; ++cc) o[cc] += e * T2[h * 32 + cc][px];
    }

    // ---- epilogue: attn tile -> Abuf[0] (A layout), Wo GEMM, direct stores ----
    const float inv = 1.f / den;
#pragma unroll
    for (int c2 = 0; c2 < 4; ++c2) {
        bf16x8 ov;
#pragma unroll
        for (int k = 0; k < 8; ++k) ov[k] = (__bf16)(o[c2 * 8 + k] * inv);
        *(bf16x8*)&Abuf[0][(h * 4 + c2) * 512 + px * 8] = ov;
    }
    __syncthreads();                          // S6: attn tile ready
    zacc();
    gemmFrags(0, wof);

    float* op = out + (size_t)b * C_DIM * HW;
#pragma unroll
    for (int i = 0; i < 4; ++i)
#pragma unroll
        for (int j = 0; j < 2; ++j) {
            const int col = wv * 32 + j * 16 + rl;
            *(f32x4*)(op + (size_t)col * HW + w0 + i * 16 + lq * 4) = acc[i][j];
        }
}

extern "C" void kernel_launch(void* const* d_in, const int* in_sizes, int n_in,
                              void* d_out, int out_size, void* d_ws, size_t ws_size,
                              hipStream_t stream)
{
    const float* x  = (const float*)d_in[0];
    const float* Wq = (const float*)d_in[1];
    const float* Wk = (const float*)d_in[2];
    const float* Wv = (const float*)d_in[3];
    const float* Wo = (const float*)d_in[4];
    (void)in_sizes; (void)n_in; (void)out_size; (void)ws_size;

    char* ws = (char*)d_ws;
    const size_t MB = 1024ull * 1024ull;
    const size_t SL = (size_t)HW * C_DIM;

    __hip_bfloat16* Wbf  = (__hip_bfloat16*)(ws);            // 512 KB
    __hip_bfloat16* xt   = (__hip_bfloat16*)(ws + 1 * MB);   // 48 MB [4*6][4096][256]
    __hip_bfloat16* xbar = (__hip_bfloat16*)(ws + 49 * MB);  // 8 MB  [4][4096][256]

    const __hip_bfloat16* WqB = Wbf;
    const __hip_bfloat16* WkB = Wbf + 65536;
    const __hip_bfloat16* WvB = Wbf + 131072;
    const __hip_bfloat16* WoB = Wbf + 196608;

    convert_weights_kernel<<<dim3(256, 4), 256, 0, stream>>>(Wq, Wk, Wv, Wo, Wbf);
    transpose_mean_kernel<<<dim3(HW / 64, C_DIM / 64, NB), 256, 0, stream>>>(x, xt, xbar);
    mega_kernel<<<dim3(HW / 64, NB), 512, 0, stream>>>(xt, xbar, WqB, WkB, WvB, WoB, (float*)d_out);
}

// Round 11
// 96.440 us; speedup vs baseline: 1.6803x; 1.0018x over previous
//
#include <hip/hip_runtime.h>
#include <hip/hip_bf16.h>

// CrossViewAttention: B=4, V=6, C=256, H=W=64 (HW=4096), heads=8, dh=32.
//
// Pipeline (3 launches):
//   1. convert_weights: Wq/Wk/Wv/Wo fp32 -> bf16
//   2. transpose_mean:  x[b][v][c][w] -> xt[b][v][w][c] bf16, xbar[b][w][c] bf16
//   3. mega_kernel: per 64-pixel tile: Q GEMM -> per view {K GEMM, scores,
//      V GEMM, online-softmax PV} -> Wo GEMM -> d_out.
//
// Round-11 change (single variable): amdgpu_waves_per_eu(2,2).
// LDS (132 KB) caps us at 1 block/CU = 2 waves/SIMD no matter what; round 10's
// compiler heuristic still allocated only 128 VGPRs and spilled the ~180-reg
// working set (weight fragments!) to scratch -> global-latency loads on the
// MFMA critical path (evidence: WRITE_SIZE 31MB vs 17MB output, VGPR=128).
// Pinning waves/EU to 2 unlocks the 256-VGPR budget so bkreg/bvreg/o/qbf
// actually stay register-resident.

typedef __bf16 bf16x8 __attribute__((ext_vector_type(8)));
typedef float f32x4 __attribute__((ext_vector_type(4)));

#define HW 4096
#define C_DIM 256
#define NV 6
#define NB 4

__global__ __launch_bounds__(256) void convert_weights_kernel(
    const float* __restrict__ Wq, const float* __restrict__ Wk,
    const float* __restrict__ Wv, const float* __restrict__ Wo,
    __hip_bfloat16* __restrict__ out)
{
    const float* srcs[4] = {Wq, Wk, Wv, Wo};
    const int m = blockIdx.y;
    const int i = blockIdx.x * 256 + threadIdx.x;
    out[m * 65536 + i] = __float2bfloat16(srcs[m][i]);
}

// 64x64 tile transpose via LDS; accumulates per-view sum for xbar.
__global__ __launch_bounds__(256) void transpose_mean_kernel(
    const float* __restrict__ x,        // [B][V][C][HW]
    __hip_bfloat16* __restrict__ xt,    // [B][V][HW][C]
    __hip_bfloat16* __restrict__ xbar)  // [B][HW][C]
{
    __shared__ float tile[64][65];
    const int w0 = blockIdx.x * 64;
    const int c0 = blockIdx.y * 64;
    const int b  = blockIdx.z;
    const int t  = threadIdx.x;
    const int li = t & 63;
    const int qi = t >> 6;
    float acc[16];
#pragma unroll
    for (int i = 0; i < 16; ++i) acc[i] = 0.f;

    for (int v = 0; v < NV; ++v) {
        const float* src = x + (((size_t)b * NV + v) * C_DIM + c0) * HW + w0;
#pragma unroll
        for (int i = 0; i < 16; ++i) {
            const int c = qi + 4 * i;
            tile[li][c] = src[(size_t)c * HW + li];
        }
        __syncthreads();
        __hip_bfloat16* dst = xt + (((size_t)b * NV + v) * HW + w0) * C_DIM + c0;
#pragma unroll
        for (int i = 0; i < 16; ++i) {
            const int w = qi + 4 * i;
            const float val = tile[w][li];
            acc[i] += val;
            dst[(size_t)w * C_DIM + li] = __float2bfloat16(val);
        }
        __syncthreads();
    }
    __hip_bfloat16* dbar = xbar + ((size_t)b * HW + w0) * C_DIM + c0;
#pragma unroll
    for (int i = 0; i < 16; ++i) {
        const int w = qi + 4 * i;
        dbar[(size_t)w * C_DIM + li] = __float2bfloat16(acc[i] * (1.f / 6.f));
    }
}

// Mega kernel: 512 threads (8 waves), block owns 64 pixels of batch b.
// Per-wave GEMM: M=64 (i<4), N=32 (j<2), K=256 (kt<8), 64 MFMA.
// LDS: Abuf 2x32KB (A tiles, [kb 0..31][row 0..63][8] bf16) + T2[256][68] f32
// (col-major C tile; 68 pad -> 16B-aligned f32x4 rows, ~2-way bank alias).
__global__ __launch_bounds__(512)
__attribute__((amdgpu_waves_per_eu(2, 2)))
void mega_kernel(
    const __hip_bfloat16* __restrict__ xt,    // [B*V][4096][256]
    const __hip_bfloat16* __restrict__ xbar,  // [B][4096][256]
    const __hip_bfloat16* __restrict__ Wq,
    const __hip_bfloat16* __restrict__ Wk,
    const __hip_bfloat16* __restrict__ Wv,
    const __hip_bfloat16* __restrict__ Wo,
    float* __restrict__ out)                  // [B][256][4096]
{
    __shared__ __align__(16) __hip_bfloat16 Abuf[2][16384];  // 64 KB
    __shared__ __align__(16) float T2[256][68];              // 68 KB
    const size_t SL = (size_t)HW * C_DIM;
    const int w0 = blockIdx.x * 64;
    const int b  = blockIdx.y;
    const int t  = threadIdx.x, wv = t >> 6, l = t & 63;
    const int kb_l = l >> 4, rl = l & 15, lq = l >> 4;
    const int px = l, h = wv;                 // softmax-phase mapping

    f32x4 acc[4][2];
    auto zacc = [&]() {
#pragma unroll
        for (int i = 0; i < 4; ++i)
#pragma unroll
            for (int j = 0; j < 2; ++j) {
                acc[i][j][0] = 0.f; acc[i][j][1] = 0.f;
                acc[i][j][2] = 0.f; acc[i][j][3] = 0.f;
            }
    };

    // stage 64x256 bf16 tile into Abuf[buf]: 32 chunks, 4 per wave
    auto stageA = [&](int buf, const __hip_bfloat16* src) {
#pragma unroll
        for (int c2 = 0; c2 < 4; ++c2) {
            const int ch = wv * 4 + c2;       // kb index 0..31
            const __hip_bfloat16* g = src + (size_t)(w0 + l) * 256 + ch * 8;
            __builtin_amdgcn_global_load_lds(
                (const __attribute__((address_space(1))) void*)g,
                (__attribute__((address_space(3))) void*)(&Abuf[buf][ch * 512]),
                16, 0, 0);
        }
    };

    // load all 16 B-fragments of a weight matrix for this wave's 32 cols
    auto preloadW = [&](const __hip_bfloat16* W, bf16x8 (&fr)[8][2]) {
#pragma unroll
        for (int kt = 0; kt < 8; ++kt)
#pragma unroll
            for (int j = 0; j < 2; ++j)
                fr[kt][j] = *(const bf16x8*)(W + (size_t)(wv * 32 + j * 16 + rl) * 256 + kt * 32 + kb_l * 8);
    };

    // GEMM with register-resident B fragments (pure LDS + MFMA)
    auto gemmFrags = [&](int buf, const bf16x8 (&fr)[8][2]) {
#pragma unroll
        for (int kt = 0; kt < 8; ++kt) {
            bf16x8 af[4];
#pragma unroll
            for (int i = 0; i < 4; ++i)
                af[i] = *(const bf16x8*)&Abuf[buf][(kt * 4 + kb_l) * 512 + (i * 16 + rl) * 8];
#pragma unroll
            for (int i = 0; i < 4; ++i)
#pragma unroll
                for (int j = 0; j < 2; ++j)
                    acc[i][j] = __builtin_amdgcn_mfma_f32_16x16x32_bf16(af[i], fr[kt][j], acc[i][j], 0, 0, 0);
        }
    };

    // acc -> T2 (col-major): 8x ds_write_b128
    auto writeT2 = [&]() {
#pragma unroll
        for (int i = 0; i < 4; ++i)
#pragma unroll
            for (int j = 0; j < 2; ++j)
                *(f32x4*)&T2[wv * 32 + j * 16 + rl][i * 16 + lq * 4] = acc[i][j];
    };

    bf16x8 bkreg[8][2], bvreg[8][2];

    // ---- prologue + Q phase ----
    stageA(0, xbar + (size_t)b * SL);
    bf16x8 wqf[8][2];
    preloadW(Wq, wqf);
    preloadW(Wk, bkreg);
    __syncthreads();                          // S0: xbar tile ready
    zacc();
    gemmFrags(0, wqf);
    stageA(1, xt + (size_t)(b * NV) * SL);    // view 0 tile (drains at S1)
    preloadW(Wv, bvreg);                      // far ahead of first gemmV
    writeT2();
    __syncthreads();                          // S1: Q in T2, xt0 staged

    // q packed bf16 (16 VGPR), scale absorbed
    const float scale = 0.17677669529663687f; // 32^-0.5
    bf16x8 qbf[4];
#pragma unroll
    for (int i = 0; i < 4; ++i)
#pragma unroll
        for (int j = 0; j < 8; ++j)
            qbf[i][j] = (__bf16)(T2[h * 32 + i * 8 + j][px] * scale);

    float m = -1e30f, den = 0.f;
    float o[32];
#pragma unroll
    for (int cc = 0; cc < 32; ++cc) o[cc] = 0.f;

    bf16x8 wof[8][2];

    // ---- view loop ----
    for (int v = 0; v < NV; ++v) {
        const int buf = (v + 1) & 1;          // v0->1, v1->0, ...
        __syncthreads();                      // S2: prior T2 reads done
        if (v < NV - 1) stageA(buf ^ 1, xt + (size_t)(b * NV + v + 1) * SL);
        zacc();
        gemmFrags(buf, bkreg);
        writeT2();
        __syncthreads();                      // S3: K in T2; next tile staged

        float s = 0.f;
#pragma unroll
        for (int i = 0; i < 4; ++i)
#pragma unroll
            for (int j = 0; j < 8; ++j)
                s += (float)qbf[i][j] * T2[h * 32 + i * 8 + j][px];
        const float mn = fmaxf(m, s);
        const float f  = __expf(m - mn);
        const float e  = __expf(s - mn);
        den = den * f + e;
        m = mn;
#pragma unroll
        for (int cc = 0; cc < 32; ++cc) o[cc] *= f;
        __syncthreads();                      // S4: score reads done, T2 free

        zacc();
        gemmFrags(buf, bvreg);
        if (v == NV - 1) preloadW(Wo, wof);   // after last bk/bv use
        writeT2();
        __syncthreads();                      // S5: V in T2
#pragma unroll
        for (int cc = 0; cc < 32; ++cc) o[cc] += e * T2[h * 32 + cc][px];
    }

    // ---- epilogue: attn tile -> Abuf[0] (A layout), Wo GEMM, direct stores ----
    const float inv = 1.f / den;
#pragma unroll
    for (int c2 = 0; c2 < 4; ++c2) {
        bf16x8 ov;
#pragma unroll
        for (int k = 0; k < 8; ++k) ov[k] = (__bf16)(o[c2 * 8 + k] * inv);
        *(bf16x8*)&Abuf[0][(h * 4 + c2) * 512 + px * 8] = ov;
    }
    __syncthreads();                          // S6: attn tile ready
    zacc();
    gemmFrags(0, wof);

    float* op = out + (size_t)b * C_DIM * HW;
#pragma unroll
    for (int i = 0; i < 4; ++i)
#pragma unroll
        for (int j = 0; j < 2; ++j) {
            const int col = wv * 32 + j * 16 + rl;
            *(f32x4*)(op + (size_t)col * HW + w0 + i * 16 + lq * 4) = acc[i][j];
        }
}

extern "C" void kernel_launch(void* const* d_in, const int* in_sizes, int n_in,
                              void* d_out, int out_size, void* d_ws, size_t ws_size,
                              hipStream_t stream)
{
    const float* x  = (const float*)d_in[0];
    const float* Wq = (const float*)d_in[1];
    const float* Wk = (const float*)d_in[2];
    const float* Wv = (const float*)d_in[3];
    const float* Wo = (const float*)d_in[4];
    (void)in_sizes; (void)n_in; (void)out_size; (void)ws_size;

    char* ws = (char*)d_ws;
    const size_t MB = 1024ull * 1024ull;
    const size_t SL = (size_t)HW * C_DIM;

    __hip_bfloat16* Wbf  = (__hip_bfloat16*)(ws);            // 512 KB
    __hip_bfloat16* xt   = (__hip_bfloat16*)(ws + 1 * MB);   // 48 MB [4*6][4096][256]
    __hip_bfloat16* xbar = (__hip_bfloat16*)(ws + 49 * MB);  // 8 MB  [4][4096][256]

    const __hip_bfloat16* WqB = Wbf;
    const __hip_bfloat16* WkB = Wbf + 65536;
    const __hip_bfloat16* WvB = Wbf + 131072;
    const __hip_bfloat16* WoB = Wbf + 196608;

    convert_weights_kernel<<<dim3(256, 4), 256, 0, stream>>>(Wq, Wk, Wv, Wo, Wbf);
    transpose_mean_kernel<<<dim3(HW / 64, C_DIM / 64, NB), 256, 0, stream>>>(x, xt, xbar);
    mega_kernel<<<dim3(HW / 64, NB), 512, 0, stream>>>(xt, xbar, WqB, WkB, WvB, WoB, (float*)d_out);
}